// Round 1
// baseline (245.258 us; speedup 1.0000x reference)
//
#include <hip/hip_runtime.h>

// SplitEmbedding: out[t, :] = (input_ids[t] in tune_ids) ? train_weight[row(t), :]
//                                                        : base_weight[input_ids[t], :]
// tune_ids is SORTED; "later duplicates win" == last matching index == upper_bound - 1.
//
// Layout: one 64-lane wave per token. D = 768 floats = 192 float4; each lane
// copies 3 float4 (lane, lane+64, lane+128). Coalesced 16B/lane loads+stores.

#define EMBED_DIM 768
#define EMBED_DIM4 (EMBED_DIM / 4)  // 192 float4 per row
#define WAVES_PER_BLOCK 4
#define BLOCK_THREADS (WAVES_PER_BLOCK * 64)

__global__ __launch_bounds__(BLOCK_THREADS) void split_embedding_kernel(
    const int* __restrict__ input_ids,    // [num_tokens]
    const int* __restrict__ tune_ids,     // [num_tune], sorted ascending
    const float* __restrict__ base_weight,   // [VOCAB, EMBED_DIM]
    const float* __restrict__ train_weight,  // [num_tune, EMBED_DIM]
    float* __restrict__ out,              // [num_tokens, EMBED_DIM]
    int num_tokens, int num_tune)
{
    const int wave = threadIdx.x >> 6;
    const int lane = threadIdx.x & 63;
    const int token = blockIdx.x * WAVES_PER_BLOCK + wave;
    if (token >= num_tokens) return;

    const int tok = input_ids[token];

    // upper_bound: first index with tune_ids[idx] > tok. Uniform across the
    // wave (all lanes search the same tok) -> broadcast loads, no divergence.
    int lo = 0, hi = num_tune;
    while (lo < hi) {
        const int mid = (lo + hi) >> 1;
        if (tune_ids[mid] <= tok) lo = mid + 1;
        else                      hi = mid;
    }
    const int cand = lo - 1;  // last index <= tok; matches "later dup wins"

    const float4* src;
    if (cand >= 0 && tune_ids[cand] == tok) {
        src = (const float4*)(train_weight + (size_t)cand * EMBED_DIM);
    } else {
        src = (const float4*)(base_weight + (size_t)tok * EMBED_DIM);
    }
    float4* dst = (float4*)(out + (size_t)token * EMBED_DIM);

    // 192 float4 per row, 64 lanes -> 3 chunks per lane, coalesced.
    #pragma unroll
    for (int i = 0; i < EMBED_DIM4 / 64; ++i) {
        const int c = lane + i * 64;
        dst[c] = src[c];
    }
}

extern "C" void kernel_launch(void* const* d_in, const int* in_sizes, int n_in,
                              void* d_out, int out_size, void* d_ws, size_t ws_size,
                              hipStream_t stream) {
    const int*   input_ids    = (const int*)d_in[0];
    const int*   tune_ids     = (const int*)d_in[1];
    const float* base_weight  = (const float*)d_in[2];
    const float* train_weight = (const float*)d_in[3];
    float*       out          = (float*)d_out;

    const int num_tokens = in_sizes[0];   // 8 * 4096 = 32768
    const int num_tune   = in_sizes[1];   // 1024

    const int grid = (num_tokens + WAVES_PER_BLOCK - 1) / WAVES_PER_BLOCK;
    split_embedding_kernel<<<grid, BLOCK_THREADS, 0, stream>>>(
        input_ids, tune_ids, base_weight, train_weight, out, num_tokens, num_tune);
}

// Round 2
// 240.630 us; speedup vs baseline: 1.0192x; 1.0192x over previous
//
#include <hip/hip_runtime.h>

// SplitEmbedding: out[t, :] = (input_ids[t] in tune_ids) ? train_weight[row(t), :]
//                                                        : base_weight[input_ids[t], :]
// tune_ids is SORTED (1024 entries); "later duplicates win" == upper_bound - 1.
//
// One 64-lane wave per token. D = 768 floats = 192 float4; each lane copies 3
// float4. Search is wave-parallel: 1024 = 64 segs x 16; round 1 probes segment
// heads (lane*16), round 2 probes within the winning segment. 2 parallel loads
// + 2 ballots replaces a 10-deep dependent binary-search chain.
// Output stores are nontemporal: 100 MB streaming write must not evict the
// gathered base_weight rows / tune_ids from L2.

#define EMBED_DIM 768
#define EMBED_DIM4 (EMBED_DIM / 4)  // 192 float4 per row
#define WAVES_PER_BLOCK 4
#define BLOCK_THREADS (WAVES_PER_BLOCK * 64)
#define NUM_TUNE_C 1024

typedef __attribute__((ext_vector_type(4))) float f4;

__global__ __launch_bounds__(BLOCK_THREADS) void split_embedding_kernel(
    const int* __restrict__ input_ids,       // [num_tokens]
    const int* __restrict__ tune_ids,        // [num_tune], sorted ascending
    const float* __restrict__ base_weight,   // [VOCAB, EMBED_DIM]
    const float* __restrict__ train_weight,  // [num_tune, EMBED_DIM]
    float* __restrict__ out,                 // [num_tokens, EMBED_DIM]
    int num_tokens, int num_tune)
{
    const int wave  = threadIdx.x >> 6;
    const int lane  = threadIdx.x & 63;
    const int token = blockIdx.x * WAVES_PER_BLOCK + wave;
    if (token >= num_tokens) return;

    const int tok = input_ids[token];   // broadcast load (same addr all lanes)

    int cand = -1;       // upper_bound(tok) - 1
    int cval = -1;       // tune_ids[cand]

    if (num_tune == NUM_TUNE_C) {
        // ---- wave-parallel 2-round search (64 x 16) ----
        // Round 1: segment heads. seg = last s with tune_ids[s*16] <= tok.
        const int v1 = tune_ids[lane << 4];
        const unsigned long long b1 = __ballot(v1 <= tok);
        const int seg = __popcll(b1) - 1;
        if (seg >= 0) {
            // Round 2: within segment. Lanes 16..63 duplicate lanes 0..15.
            const int v2 = tune_ids[(seg << 4) + (lane & 15)];
            const unsigned long long b2 = __ballot(v2 <= tok) & 0xFFFFull;
            const int cnt = __popcll(b2);           // >= 1 (head qualifies)
            cand = (seg << 4) + cnt - 1;
            cval = __shfl(v2, cand & 15);
        }
    } else {
        // Generic fallback: serial binary search (wave-uniform).
        int lo = 0, hi = num_tune;
        while (lo < hi) {
            const int mid = (lo + hi) >> 1;
            if (tune_ids[mid] <= tok) lo = mid + 1;
            else                      hi = mid;
        }
        cand = lo - 1;
        if (cand >= 0) cval = tune_ids[cand];
    }

    const f4* src;
    if (cand >= 0 && cval == tok) {
        src = (const f4*)(train_weight + (size_t)cand * EMBED_DIM);
    } else {
        src = (const f4*)(base_weight + (size_t)tok * EMBED_DIM);
    }
    f4* dst = (f4*)(out + (size_t)token * EMBED_DIM);

    // 192 float4 per row, 64 lanes -> 3 chunks per lane, coalesced.
    f4 r0 = src[lane];
    f4 r1 = src[lane + 64];
    f4 r2 = src[lane + 128];
    __builtin_nontemporal_store(r0, dst + lane);
    __builtin_nontemporal_store(r1, dst + lane + 64);
    __builtin_nontemporal_store(r2, dst + lane + 128);
}

extern "C" void kernel_launch(void* const* d_in, const int* in_sizes, int n_in,
                              void* d_out, int out_size, void* d_ws, size_t ws_size,
                              hipStream_t stream) {
    const int*   input_ids    = (const int*)d_in[0];
    const int*   tune_ids     = (const int*)d_in[1];
    const float* base_weight  = (const float*)d_in[2];
    const float* train_weight = (const float*)d_in[3];
    float*       out          = (float*)d_out;

    const int num_tokens = in_sizes[0];   // 8 * 4096 = 32768
    const int num_tune   = in_sizes[1];   // 1024

    const int grid = (num_tokens + WAVES_PER_BLOCK - 1) / WAVES_PER_BLOCK;
    split_embedding_kernel<<<grid, BLOCK_THREADS, 0, stream>>>(
        input_ids, tune_ids, base_weight, train_weight, out, num_tokens, num_tune);
}